// Round 1
// baseline (494.525 us; speedup 1.0000x reference)
//
#include <hip/hip_runtime.h>
#include <stdint.h>

#define S_LEN 1024
#define DH 128
#define QT 32
#define KA 64
#define NTHREADS 512
#define SCALE 0.08838834764831845f

typedef __attribute__((ext_vector_type(8))) short bf16x8;
typedef __attribute__((ext_vector_type(4))) float f32x4;

__device__ __forceinline__ unsigned short f2bf(float f) {
    union { float f; unsigned u; } c; c.f = f;
    unsigned u = c.u;
    u += 0x7FFFu + ((u >> 16) & 1u);   // round-to-nearest-even
    return (unsigned short)(u >> 16);
}

// One block = one (b,h) and 32 query rows. 8 waves (512 threads).
// LDS: full 32x1024 f32 score tile (XOR-swizzled), plus a 64x128 bf16 K tile.
__global__ __launch_bounds__(NTHREADS, 1)
void attn_fused(const float* __restrict__ Q, const float* __restrict__ K,
                const float* __restrict__ V, const int* __restrict__ M,
                float* __restrict__ Obuf, float* __restrict__ Abuf)
{
    __shared__ float s_lds[QT * S_LEN];            // 128 KB, swizzle: col ^ ((row&7)<<2) (dword granules of 4)
    __shared__ unsigned short k_lds[KA * DH];      // 16 KB bf16, swizzle: d ^ ((k&7)<<3)
    __shared__ float inv_l[QT];

    const int tid  = threadIdx.x;
    const int lane = tid & 63;
    const int wave = tid >> 6;
    const int l15  = lane & 15;
    const int l4   = lane >> 4;

    const int bh = blockIdx.x >> 5;        // 0..63  (b*16+h)
    const int qt = blockIdx.x & 31;        // q-tile index
    const int b  = bh >> 4;
    const int q0 = qt * QT;

    const float* Qb = Q + ((size_t)bh * S_LEN + q0) * DH;
    const float* Kb = K + (size_t)bh * S_LEN * DH;
    const float* Vb = V + (size_t)bh * S_LEN * DH;
    const int*   Mb = M + ((size_t)b * S_LEN + q0) * S_LEN;   // mask is [B,1,S,S]
    float* Ob = Obuf + ((size_t)bh * S_LEN + q0) * DH;
    float* Ab = Abuf + ((size_t)bh * S_LEN + q0) * S_LEN;

    const int wq = wave & 1;   // which 16-row q sub-tile
    const int wk = wave >> 1;  // phase A: which 16-col k sub-tile (of KA=64); phase C: d-group

    // ---- preload Q fragments as bf16 (A-operand: row=lane&15, k=8*(lane>>4)+e) ----
    bf16x8 qfrag[4];
    {
        const float* qrow = Qb + (wq * 16 + l15) * DH + 8 * l4;
        #pragma unroll
        for (int c = 0; c < 4; ++c) {
            const float4 a  = *(const float4*)(qrow + c * 32);
            const float4 bb = *(const float4*)(qrow + c * 32 + 4);
            bf16x8 f;
            f[0]=(short)f2bf(a.x);  f[1]=(short)f2bf(a.y);  f[2]=(short)f2bf(a.z);  f[3]=(short)f2bf(a.w);
            f[4]=(short)f2bf(bb.x); f[5]=(short)f2bf(bb.y); f[6]=(short)f2bf(bb.z); f[7]=(short)f2bf(bb.w);
            qfrag[c] = f;
        }
    }

    // ---- Phase A: scores = Q K^T -> s_lds (raw, unscaled) ----
    for (int kb = 0; kb < S_LEN; kb += KA) {
        // stage K[kb..kb+64) as bf16 into k_lds (coalesced float4 reads)
        #pragma unroll
        for (int it = 0; it < (KA * DH / 4) / NTHREADS; ++it) {   // 4 iters
            int fidx = tid + it * NTHREADS;       // float4 index
            int k  = fidx >> 5;                   // 32 float4 per row
            int d4 = (fidx & 31) * 4;
            float4 v = *(const float4*)(Kb + (size_t)(kb + k) * DH + d4);
            int idx = k * DH + (d4 ^ ((k & 7) << 3));
            ushort4 w = make_ushort4(f2bf(v.x), f2bf(v.y), f2bf(v.z), f2bf(v.w));
            *(ushort4*)&k_lds[idx] = w;
        }
        __syncthreads();

        f32x4 acc = {0.f, 0.f, 0.f, 0.f};
        #pragma unroll
        for (int c = 0; c < 4; ++c) {
            int kr = wk * 16 + l15;               // score column (key index) for this lane
            int d  = c * 32 + 8 * l4;
            bf16x8 kf = *(const bf16x8*)&k_lds[kr * DH + (d ^ ((kr & 7) << 3))];
            acc = __builtin_amdgcn_mfma_f32_16x16x32_bf16(qfrag[c], kf, acc, 0, 0, 0);
        }
        // C/D layout: col = lane&15, row = (lane>>4)*4 + r
        int col = kb + wk * 16 + l15;
        #pragma unroll
        for (int r = 0; r < 4; ++r) {
            int row = wq * 16 + l4 * 4 + r;
            s_lds[row * S_LEN + (col ^ ((row & 7) << 2))] = acc[r];
        }
        __syncthreads();
    }

    // ---- Phase B0: apply scale + mask (coalesced int4/float4) ----
    #pragma unroll 4
    for (int it = 0; it < 16; ++it) {
        int idx4 = (tid + it * NTHREADS) * 4;
        int row = idx4 >> 10;
        int col = idx4 & (S_LEN - 1);
        int si  = row * S_LEN + (col ^ ((row & 7) << 2));
        int4  mm = *(const int4*)(Mb + idx4);
        float4 s = *(const float4*)&s_lds[si];
        s.x = mm.x ? s.x * SCALE : -1e9f;
        s.y = mm.y ? s.y * SCALE : -1e9f;
        s.z = mm.z ? s.z * SCALE : -1e9f;
        s.w = mm.w ? s.w * SCALE : -1e9f;
        *(float4*)&s_lds[si] = s;
    }
    __syncthreads();

    // ---- Phase B: row softmax (16 lanes per row, shuffle reduce) ----
    {
        int row = tid >> 4, sub = tid & 15;
        const int sw = (row & 7) << 2;
        float* srow = &s_lds[row * S_LEN];
        float mx = -3.0e38f;
        #pragma unroll 4
        for (int j = 0; j < 16; ++j) {
            int ci = (j * 64 + sub * 4) ^ sw;
            float4 s = *(const float4*)(srow + ci);
            mx = fmaxf(mx, fmaxf(fmaxf(s.x, s.y), fmaxf(s.z, s.w)));
        }
        #pragma unroll
        for (int o = 8; o >= 1; o >>= 1) mx = fmaxf(mx, __shfl_xor(mx, o, 16));
        float sum = 0.f;
        #pragma unroll 4
        for (int j = 0; j < 16; ++j) {
            int ci = (j * 64 + sub * 4) ^ sw;
            float4 s = *(const float4*)(srow + ci);
            float4 e = make_float4(__expf(s.x - mx), __expf(s.y - mx),
                                   __expf(s.z - mx), __expf(s.w - mx));
            *(float4*)(srow + ci) = e;
            sum += e.x + e.y + e.z + e.w;
        }
        #pragma unroll
        for (int o = 8; o >= 1; o >>= 1) sum += __shfl_xor(sum, o, 16);
        if (sub == 0) inv_l[row] = 1.0f / sum;
    }
    __syncthreads();

    // ---- Phase C1: store normalized attention (coalesced float4) ----
    #pragma unroll 4
    for (int it = 0; it < 16; ++it) {
        int idx4 = (tid + it * NTHREADS) * 4;
        int row = idx4 >> 10;
        int col = idx4 & (S_LEN - 1);
        float il = inv_l[row];
        float4 s = *(const float4*)&s_lds[row * S_LEN + (col ^ ((row & 7) << 2))];
        *(float4*)(Ab + idx4) = make_float4(s.x * il, s.y * il, s.z * il, s.w * il);
    }

    // ---- Phase C2: out = P V (P unnormalized in s_lds; scale by 1/l at end) ----
    const int wd = wave >> 1;   // 4 d-groups of 32
    f32x4 o0 = {0.f,0.f,0.f,0.f}, o1 = {0.f,0.f,0.f,0.f};
    for (int kc = 0; kc < S_LEN; kc += 32) {
        int prow = wq * 16 + l15;
        int cb = kc + 8 * l4;
        const float* sp = &s_lds[prow * S_LEN];
        int sw = (prow & 7) << 2;
        float4 p0 = *(const float4*)(sp + (cb ^ sw));
        float4 p1 = *(const float4*)(sp + ((cb + 4) ^ sw));
        bf16x8 pa;
        pa[0]=(short)f2bf(p0.x); pa[1]=(short)f2bf(p0.y); pa[2]=(short)f2bf(p0.z); pa[3]=(short)f2bf(p0.w);
        pa[4]=(short)f2bf(p1.x); pa[5]=(short)f2bf(p1.y); pa[6]=(short)f2bf(p1.z); pa[7]=(short)f2bf(p1.w);
        const float* vbase = Vb + (size_t)(kc + 8 * l4) * DH;
        {
            const float* vp = vbase + wd * 32 + l15;
            bf16x8 vf;
            #pragma unroll
            for (int e = 0; e < 8; ++e) vf[e] = (short)f2bf(vp[(size_t)e * DH]);
            o0 = __builtin_amdgcn_mfma_f32_16x16x32_bf16(pa, vf, o0, 0, 0, 0);
        }
        {
            const float* vp = vbase + wd * 32 + 16 + l15;
            bf16x8 vf;
            #pragma unroll
            for (int e = 0; e < 8; ++e) vf[e] = (short)f2bf(vp[(size_t)e * DH]);
            o1 = __builtin_amdgcn_mfma_f32_16x16x32_bf16(pa, vf, o1, 0, 0, 0);
        }
    }
    #pragma unroll
    for (int r = 0; r < 4; ++r) {
        int row = wq * 16 + l4 * 4 + r;
        float il = inv_l[row];
        Ob[row * DH + wd * 32 + l15]      = o0[r] * il;
        Ob[row * DH + wd * 32 + 16 + l15] = o1[r] * il;
    }
}

extern "C" void kernel_launch(void* const* d_in, const int* in_sizes, int n_in,
                              void* d_out, int out_size, void* d_ws, size_t ws_size,
                              hipStream_t stream) {
    const float* Q = (const float*)d_in[0];
    const float* K = (const float*)d_in[1];
    const float* V = (const float*)d_in[2];
    const int*   M = (const int*)d_in[3];
    float* out  = (float*)d_out;
    float* attn = out + (size_t)4 * 16 * 1024 * 128;   // out first, then attention
    dim3 grid(4 * 16 * (1024 / QT));                   // 2048 blocks
    attn_fused<<<grid, NTHREADS, 0, stream>>>(Q, K, V, M, out, attn);
}

// Round 2
// 286.245 us; speedup vs baseline: 1.7276x; 1.7276x over previous
//
#include <hip/hip_runtime.h>
#include <hip/hip_bf16.h>
#include <stdint.h>

#define S_LEN 1024
#define DH 128
#define QT 32
#define KA 64
#define NTHREADS 512
#define SCALE 0.08838834764831845f
#define NBH 64

typedef __attribute__((ext_vector_type(8))) short bf16x8;
typedef __attribute__((ext_vector_type(4))) float f32x4;

__device__ __forceinline__ unsigned short f2bf(float f) {
    __hip_bfloat16 h = __float2bfloat16(f);
    unsigned short r;
    __builtin_memcpy(&r, &h, 2);
    return r;
}

// ---------------- pre-pass 1: K f32 [bh][s][d] -> bf16 same layout ----------------
__global__ __launch_bounds__(256)
void convert_k(const float* __restrict__ K, unsigned short* __restrict__ Kb) {
    size_t i = ((size_t)blockIdx.x * 256 + threadIdx.x) * 8;
    float4 a = *(const float4*)(K + i);
    float4 b = *(const float4*)(K + i + 4);
    bf16x8 w;
    w[0]=(short)f2bf(a.x); w[1]=(short)f2bf(a.y); w[2]=(short)f2bf(a.z); w[3]=(short)f2bf(a.w);
    w[4]=(short)f2bf(b.x); w[5]=(short)f2bf(b.y); w[6]=(short)f2bf(b.z); w[7]=(short)f2bf(b.w);
    *(bf16x8*)(Kb + i) = w;
}

// ---------------- pre-pass 2: V f32 [bh][s][d] -> bf16 transposed [bh][d][s] ------
#define TS 64
#define TP (TS + 4)
__global__ __launch_bounds__(512)
void transpose_v(const float* __restrict__ V, unsigned short* __restrict__ Vt) {
    __shared__ unsigned short t[DH * TP];
    const int tid = threadIdx.x;
    const int bh = blockIdx.x >> 4;
    const int s0 = (blockIdx.x & 15) * TS;
    const float* Vb = V + ((size_t)bh * S_LEN + s0) * DH;
    #pragma unroll
    for (int it = 0; it < 4; ++it) {
        int fidx = tid + it * 512;            // float4 index; 32 per s-row
        int s = fidx >> 5, d4 = (fidx & 31) * 4;
        float4 v = *(const float4*)(Vb + s * DH + d4);
        t[(d4 + 0) * TP + s] = f2bf(v.x);
        t[(d4 + 1) * TP + s] = f2bf(v.y);
        t[(d4 + 2) * TP + s] = f2bf(v.z);
        t[(d4 + 3) * TP + s] = f2bf(v.w);
    }
    __syncthreads();
    unsigned short* Vtb = Vt + (size_t)bh * DH * S_LEN + s0;
    #pragma unroll
    for (int it = 0; it < 4; ++it) {
        int cidx = tid + it * 512;            // ushort4 chunk: 128 d-rows x 16 chunks
        int d = cidx >> 4, sc = (cidx & 15) * 4;
        ushort4 w = *(ushort4*)&t[d * TP + sc];
        *(ushort4*)(Vtb + (size_t)d * S_LEN + sc) = w;
    }
}

// ---------------- main fused kernel ----------------
__global__ __launch_bounds__(NTHREADS, 1)
void attn_fused2(const float* __restrict__ Q, const unsigned short* __restrict__ K16,
                 const unsigned short* __restrict__ Vt, const int* __restrict__ M,
                 float* __restrict__ Obuf, float* __restrict__ Abuf)
{
    __shared__ float s_lds[QT * S_LEN];            // 128 KB raw scores (f32, swizzled)
    __shared__ unsigned short k_lds[KA * DH];      // 16 KB bf16 K tile (swizzled)
    __shared__ float inv_l[QT];

    const int tid  = threadIdx.x;
    const int lane = tid & 63;
    const int wave = tid >> 6;
    const int l15  = lane & 15;
    const int l4   = lane >> 4;

    // XCD-aware swizzle: 2048 blocks, 8 XCDs -> 256 contiguous per XCD (8 heads each)
    const int bid = ((blockIdx.x & 7) << 8) | (blockIdx.x >> 3);
    const int bh = bid >> 5;
    const int qt = bid & 31;
    const int b  = bh >> 4;
    const int q0 = qt * QT;

    const float* Qb = Q + ((size_t)bh * S_LEN + q0) * DH;
    const unsigned short* Kbh = K16 + (size_t)bh * S_LEN * DH;
    const unsigned short* Vbh = Vt + (size_t)bh * DH * S_LEN;
    const int*   Mb = M + ((size_t)b * S_LEN + q0) * S_LEN;
    float* Ob = Obuf + ((size_t)bh * S_LEN + q0) * DH;
    float* Ab = Abuf + ((size_t)bh * S_LEN + q0) * S_LEN;

    const int wq = wave & 1;
    const int wk = wave >> 1;

    // ---- Q fragments (A-operand: row=lane&15, k=8*(lane>>4)+e) ----
    bf16x8 qfrag[4];
    {
        const float* qrow = Qb + (wq * 16 + l15) * DH + 8 * l4;
        #pragma unroll
        for (int c = 0; c < 4; ++c) {
            const float4 a  = *(const float4*)(qrow + c * 32);
            const float4 bb = *(const float4*)(qrow + c * 32 + 4);
            bf16x8 f;
            f[0]=(short)f2bf(a.x);  f[1]=(short)f2bf(a.y);  f[2]=(short)f2bf(a.z);  f[3]=(short)f2bf(a.w);
            f[4]=(short)f2bf(bb.x); f[5]=(short)f2bf(bb.y); f[6]=(short)f2bf(bb.z); f[7]=(short)f2bf(bb.w);
            qfrag[c] = f;
        }
    }

    // ---- Phase A: scores = Q K^T -> s_lds f32 (K staged bf16, reg double-buffered) ----
    // chunk mapping: fidx = tid + it*512 -> k-row = fidx>>4, col8 = (fidx&15)*8
    const int kr0 = tid >> 4,        c0 = (tid & 15) * 8;
    const int kr1 = (tid + 512) >> 4, c1 = (tid & 15) * 8;
    bf16x8 st0 = *(const bf16x8*)(Kbh + (size_t)kr0 * DH + c0);
    bf16x8 st1 = *(const bf16x8*)(Kbh + (size_t)kr1 * DH + c1);
    for (int ti = 0; ti < S_LEN / KA; ++ti) {
        *(bf16x8*)&k_lds[kr0 * DH + (c0 ^ ((kr0 & 7) << 3))] = st0;
        *(bf16x8*)&k_lds[kr1 * DH + (c1 ^ ((kr1 & 7) << 3))] = st1;
        __syncthreads();
        if (ti + 1 < S_LEN / KA) {
            const unsigned short* nk = Kbh + (size_t)(ti + 1) * KA * DH;
            st0 = *(const bf16x8*)(nk + (size_t)kr0 * DH + c0);
            st1 = *(const bf16x8*)(nk + (size_t)kr1 * DH + c1);
        }
        f32x4 acc = {0.f, 0.f, 0.f, 0.f};
        #pragma unroll
        for (int c = 0; c < 4; ++c) {
            int kr = wk * 16 + l15;
            int d  = c * 32 + 8 * l4;
            bf16x8 kf = *(const bf16x8*)&k_lds[kr * DH + (d ^ ((kr & 7) << 3))];
            acc = __builtin_amdgcn_mfma_f32_16x16x32_bf16(qfrag[c], kf, acc, 0, 0, 0);
        }
        int col = ti * KA + wk * 16 + l15;
        #pragma unroll
        for (int r = 0; r < 4; ++r) {
            int row = wq * 16 + l4 * 4 + r;
            s_lds[row * S_LEN + (col ^ ((row & 7) << 2))] = acc[r];
        }
        __syncthreads();
    }

    // ---- Phase B: mask+scale+softmax entirely through registers ----
    const int row = tid >> 4;
    const int sub = tid & 15;
    const int sw  = (row & 7) << 2;
    const int psw = (row & 7) << 3;        // bf16 P swizzle (shorts)
    float* srow = s_lds + row * S_LEN;
    const int* mrow = Mb + row * S_LEN;

    float4 v[16];
    float mx = -3.0e38f;
    #pragma unroll
    for (int j = 0; j < 16; ++j) {
        int tc = j * 64 + sub * 4;
        int4  mm = *(const int4*)(mrow + tc);
        float4 s = *(const float4*)(srow + (tc ^ sw));
        s.x = mm.x ? s.x * SCALE : -1e9f;
        s.y = mm.y ? s.y * SCALE : -1e9f;
        s.z = mm.z ? s.z * SCALE : -1e9f;
        s.w = mm.w ? s.w * SCALE : -1e9f;
        v[j] = s;
        mx = fmaxf(mx, fmaxf(fmaxf(s.x, s.y), fmaxf(s.z, s.w)));
    }
    #pragma unroll
    for (int o = 8; o >= 1; o >>= 1) mx = fmaxf(mx, __shfl_xor(mx, o, 16));
    float sum = 0.f;
    #pragma unroll
    for (int j = 0; j < 16; ++j) {
        float4 e = make_float4(__expf(v[j].x - mx), __expf(v[j].y - mx),
                               __expf(v[j].z - mx), __expf(v[j].w - mx));
        v[j] = e;
        sum += (e.x + e.y) + (e.z + e.w);
    }
    #pragma unroll
    for (int o = 8; o >= 1; o >>= 1) sum += __shfl_xor(sum, o, 16);
    const float il = 1.0f / sum;
    if (sub == 0) inv_l[row] = il;
    __syncthreads();   // all raw-score reads complete before bf16 P overwrites

    // write normalized attention (global, f32) + unnormalized bf16 P into s_lds front
    {
        unsigned short* p_w = (unsigned short*)s_lds;
        float* arow = Ab + row * S_LEN;
        #pragma unroll
        for (int j = 0; j < 16; ++j) {
            int tc = j * 64 + sub * 4;
            float4 e = v[j];
            *(float4*)(arow + tc) = make_float4(e.x * il, e.y * il, e.z * il, e.w * il);
            ushort4 pw = make_ushort4(f2bf(e.x), f2bf(e.y), f2bf(e.z), f2bf(e.w));
            *(ushort4*)&p_w[row * S_LEN + (tc ^ psw)] = pw;
        }
    }
    __syncthreads();

    // ---- Phase C: out = P V  (P bf16 in LDS, V bf16 pre-transposed in global) ----
    const int wd = wave >> 1;
    const int prow = wq * 16 + l15;
    const int ppsw = (prow & 7) << 3;
    const unsigned short* p_lds = (const unsigned short*)s_lds;
    const unsigned short* vrow0 = Vbh + (size_t)(wd * 32 + l15) * S_LEN;
    const unsigned short* vrow1 = vrow0 + (size_t)16 * S_LEN;
    f32x4 o0 = {0.f,0.f,0.f,0.f}, o1 = {0.f,0.f,0.f,0.f};
    #pragma unroll 4
    for (int kc = 0; kc < S_LEN; kc += 32) {
        int kk = kc + 8 * l4;
        bf16x8 pa  = *(const bf16x8*)&p_lds[prow * S_LEN + (kk ^ ppsw)];
        bf16x8 vf0 = *(const bf16x8*)(vrow0 + kk);
        bf16x8 vf1 = *(const bf16x8*)(vrow1 + kk);
        o0 = __builtin_amdgcn_mfma_f32_16x16x32_bf16(pa, vf0, o0, 0, 0, 0);
        o1 = __builtin_amdgcn_mfma_f32_16x16x32_bf16(pa, vf1, o1, 0, 0, 0);
    }
    #pragma unroll
    for (int r = 0; r < 4; ++r) {
        int orow = wq * 16 + l4 * 4 + r;
        float oil = inv_l[orow];
        Ob[orow * DH + wd * 32 + l15]      = o0[r] * oil;
        Ob[orow * DH + wd * 32 + 16 + l15] = o1[r] * oil;
    }
}

// ---------------- round-1 fallback (used only if ws_size too small) ----------------
__device__ __forceinline__ unsigned short f2bf_m(float f) {
    union { float f; unsigned u; } c; c.f = f;
    unsigned u = c.u;
    u += 0x7FFFu + ((u >> 16) & 1u);
    return (unsigned short)(u >> 16);
}

__global__ __launch_bounds__(NTHREADS, 1)
void attn_fused(const float* __restrict__ Q, const float* __restrict__ K,
                const float* __restrict__ V, const int* __restrict__ M,
                float* __restrict__ Obuf, float* __restrict__ Abuf)
{
    __shared__ float s_lds[QT * S_LEN];
    __shared__ unsigned short k_lds[KA * DH];
    __shared__ float inv_l[QT];

    const int tid  = threadIdx.x;
    const int lane = tid & 63;
    const int wave = tid >> 6;
    const int l15  = lane & 15;
    const int l4   = lane >> 4;

    const int bh = blockIdx.x >> 5;
    const int qt = blockIdx.x & 31;
    const int b  = bh >> 4;
    const int q0 = qt * QT;

    const float* Qb = Q + ((size_t)bh * S_LEN + q0) * DH;
    const float* Kb = K + (size_t)bh * S_LEN * DH;
    const float* Vb = V + (size_t)bh * S_LEN * DH;
    const int*   Mb = M + ((size_t)b * S_LEN + q0) * S_LEN;
    float* Ob = Obuf + ((size_t)bh * S_LEN + q0) * DH;
    float* Ab = Abuf + ((size_t)bh * S_LEN + q0) * S_LEN;

    const int wq = wave & 1;
    const int wk = wave >> 1;

    bf16x8 qfrag[4];
    {
        const float* qrow = Qb + (wq * 16 + l15) * DH + 8 * l4;
        #pragma unroll
        for (int c = 0; c < 4; ++c) {
            const float4 a  = *(const float4*)(qrow + c * 32);
            const float4 bb = *(const float4*)(qrow + c * 32 + 4);
            bf16x8 f;
            f[0]=(short)f2bf_m(a.x);  f[1]=(short)f2bf_m(a.y);  f[2]=(short)f2bf_m(a.z);  f[3]=(short)f2bf_m(a.w);
            f[4]=(short)f2bf_m(bb.x); f[5]=(short)f2bf_m(bb.y); f[6]=(short)f2bf_m(bb.z); f[7]=(short)f2bf_m(bb.w);
            qfrag[c] = f;
        }
    }

    for (int kb = 0; kb < S_LEN; kb += KA) {
        #pragma unroll
        for (int it = 0; it < (KA * DH / 4) / NTHREADS; ++it) {
            int fidx = tid + it * NTHREADS;
            int k  = fidx >> 5;
            int d4 = (fidx & 31) * 4;
            float4 v = *(const float4*)(Kb + (size_t)(kb + k) * DH + d4);
            int idx = k * DH + (d4 ^ ((k & 7) << 3));
            ushort4 w = make_ushort4(f2bf_m(v.x), f2bf_m(v.y), f2bf_m(v.z), f2bf_m(v.w));
            *(ushort4*)&k_lds[idx] = w;
        }
        __syncthreads();

        f32x4 acc = {0.f, 0.f, 0.f, 0.f};
        #pragma unroll
        for (int c = 0; c < 4; ++c) {
            int kr = wk * 16 + l15;
            int d  = c * 32 + 8 * l4;
            bf16x8 kf = *(const bf16x8*)&k_lds[kr * DH + (d ^ ((kr & 7) << 3))];
            acc = __builtin_amdgcn_mfma_f32_16x16x32_bf16(qfrag[c], kf, acc, 0, 0, 0);
        }
        int col = kb + wk * 16 + l15;
        #pragma unroll
        for (int r = 0; r < 4; ++r) {
            int row = wq * 16 + l4 * 4 + r;
            s_lds[row * S_LEN + (col ^ ((row & 7) << 2))] = acc[r];
        }
        __syncthreads();
    }

    #pragma unroll 4
    for (int it = 0; it < 16; ++it) {
        int idx4 = (tid + it * NTHREADS) * 4;
        int row = idx4 >> 10;
        int col = idx4 & (S_LEN - 1);
        int si  = row * S_LEN + (col ^ ((row & 7) << 2));
        int4  mm = *(const int4*)(Mb + idx4);
        float4 s = *(const float4*)&s_lds[si];
        s.x = mm.x ? s.x * SCALE : -1e9f;
        s.y = mm.y ? s.y * SCALE : -1e9f;
        s.z = mm.z ? s.z * SCALE : -1e9f;
        s.w = mm.w ? s.w * SCALE : -1e9f;
        *(float4*)&s_lds[si] = s;
    }
    __syncthreads();

    {
        int row = tid >> 4, sub = tid & 15;
        const int sw = (row & 7) << 2;
        float* srow = &s_lds[row * S_LEN];
        float mx = -3.0e38f;
        #pragma unroll 4
        for (int j = 0; j < 16; ++j) {
            int ci = (j * 64 + sub * 4) ^ sw;
            float4 s = *(const float4*)(srow + ci);
            mx = fmaxf(mx, fmaxf(fmaxf(s.x, s.y), fmaxf(s.z, s.w)));
        }
        #pragma unroll
        for (int o = 8; o >= 1; o >>= 1) mx = fmaxf(mx, __shfl_xor(mx, o, 16));
        float sum = 0.f;
        #pragma unroll 4
        for (int j = 0; j < 16; ++j) {
            int ci = (j * 64 + sub * 4) ^ sw;
            float4 s = *(const float4*)(srow + ci);
            float4 e = make_float4(__expf(s.x - mx), __expf(s.y - mx),
                                   __expf(s.z - mx), __expf(s.w - mx));
            *(float4*)(srow + ci) = e;
            sum += e.x + e.y + e.z + e.w;
        }
        #pragma unroll
        for (int o = 8; o >= 1; o >>= 1) sum += __shfl_xor(sum, o, 16);
        if (sub == 0) inv_l[row] = 1.0f / sum;
    }
    __syncthreads();

    #pragma unroll 4
    for (int it = 0; it < 16; ++it) {
        int idx4 = (tid + it * NTHREADS) * 4;
        int row = idx4 >> 10;
        int col = idx4 & (S_LEN - 1);
        float ilv = inv_l[row];
        float4 s = *(const float4*)&s_lds[row * S_LEN + (col ^ ((row & 7) << 2))];
        *(float4*)(Ab + idx4) = make_float4(s.x * ilv, s.y * ilv, s.z * ilv, s.w * ilv);
    }

    const int wd = wave >> 1;
    f32x4 o0 = {0.f,0.f,0.f,0.f}, o1 = {0.f,0.f,0.f,0.f};
    for (int kc = 0; kc < S_LEN; kc += 32) {
        int prow = wq * 16 + l15;
        int cb = kc + 8 * l4;
        const float* sp = &s_lds[prow * S_LEN];
        int swp = (prow & 7) << 2;
        float4 p0 = *(const float4*)(sp + (cb ^ swp));
        float4 p1 = *(const float4*)(sp + ((cb + 4) ^ swp));
        bf16x8 pa;
        pa[0]=(short)f2bf_m(p0.x); pa[1]=(short)f2bf_m(p0.y); pa[2]=(short)f2bf_m(p0.z); pa[3]=(short)f2bf_m(p0.w);
        pa[4]=(short)f2bf_m(p1.x); pa[5]=(short)f2bf_m(p1.y); pa[6]=(short)f2bf_m(p1.z); pa[7]=(short)f2bf_m(p1.w);
        const float* vbase = Vb + (size_t)(kc + 8 * l4) * DH;
        {
            const float* vp = vbase + wd * 32 + l15;
            bf16x8 vf;
            #pragma unroll
            for (int e = 0; e < 8; ++e) vf[e] = (short)f2bf_m(vp[(size_t)e * DH]);
            o0 = __builtin_amdgcn_mfma_f32_16x16x32_bf16(pa, vf, o0, 0, 0, 0);
        }
        {
            const float* vp = vbase + wd * 32 + 16 + l15;
            bf16x8 vf;
            #pragma unroll
            for (int e = 0; e < 8; ++e) vf[e] = (short)f2bf_m(vp[(size_t)e * DH]);
            o1 = __builtin_amdgcn_mfma_f32_16x16x32_bf16(pa, vf, o1, 0, 0, 0);
        }
    }
    #pragma unroll
    for (int r = 0; r < 4; ++r) {
        int row = wq * 16 + l4 * 4 + r;
        float ilv = inv_l[row];
        Ob[row * DH + wd * 32 + l15]      = o0[r] * ilv;
        Ob[row * DH + wd * 32 + 16 + l15] = o1[r] * ilv;
    }
}

extern "C" void kernel_launch(void* const* d_in, const int* in_sizes, int n_in,
                              void* d_out, int out_size, void* d_ws, size_t ws_size,
                              hipStream_t stream) {
    const float* Q = (const float*)d_in[0];
    const float* K = (const float*)d_in[1];
    const float* V = (const float*)d_in[2];
    const int*   M = (const int*)d_in[3];
    float* out  = (float*)d_out;
    float* attn = out + (size_t)NBH * S_LEN * DH;

    const size_t half = (size_t)NBH * S_LEN * DH;             // elements per tensor
    const size_t need = 2 * half * sizeof(unsigned short);    // 33.5 MB
    if (ws_size >= need) {
        unsigned short* K16 = (unsigned short*)d_ws;
        unsigned short* Vt  = K16 + half;
        convert_k<<<dim3((unsigned)(half / (256 * 8))), 256, 0, stream>>>(K, K16);
        transpose_v<<<dim3(NBH * (S_LEN / TS)), 512, 0, stream>>>(V, Vt);
        attn_fused2<<<dim3(NBH * (S_LEN / QT)), NTHREADS, 0, stream>>>(Q, K16, Vt, M, out, attn);
    } else {
        attn_fused<<<dim3(NBH * (S_LEN / QT)), NTHREADS, 0, stream>>>(Q, K, V, M, out, attn);
    }
}